// Round 5
// baseline (953.859 us; speedup 1.0000x reference)
//
#include <hip/hip_runtime.h>
#include <hip/hip_bf16.h>

#define BDIM 4096
#define DDIM 1024
#define NPAIRS 5
#define TW 16            // 4096/256 tiles per side
#define KT32 32          // 1024/32 K-tiles
#define RSH 8192         // shorts per 256x32 buffer

typedef __attribute__((ext_vector_type(8))) short short8;
typedef __attribute__((ext_vector_type(4))) float floatx4;

__device__ __forceinline__ void gload16(const void* g, void* l) {
    __builtin_amdgcn_global_load_lds((const __attribute__((address_space(1))) void*)g,
                                     (__attribute__((address_space(3))) void*)l, 16, 0, 0);
}

__device__ __forceinline__ unsigned short f2bf(float f) {
    unsigned u = __float_as_uint(f);
    u = (u + 0x7FFFu + ((u >> 16) & 1u)) >> 16;   // RNE f32->bf16
    return (unsigned short)u;
}

// ---------------- cast f32 -> bf16, 4 matrices ----------------
__global__ void cast_kernel(const float* __restrict__ t, const float* __restrict__ im,
                            const float* __restrict__ au, const float* __restrict__ de,
                            short* __restrict__ out) {
    const float* src;
    switch (blockIdx.y) {
        case 0: src = t; break;
        case 1: src = im; break;
        case 2: src = au; break;
        default: src = de; break;
    }
    short* dst = out + (size_t)blockIdx.y * (BDIM * DDIM);
    int idx = (blockIdx.x * 256 + threadIdx.x) * 8;
    float4 f0 = *(const float4*)(src + idx);
    float4 f1 = *(const float4*)(src + idx + 4);
    short8 r;
    r[0] = (short)f2bf(f0.x); r[1] = (short)f2bf(f0.y);
    r[2] = (short)f2bf(f0.z); r[3] = (short)f2bf(f0.w);
    r[4] = (short)f2bf(f1.x); r[5] = (short)f2bf(f1.y);
    r[6] = (short)f2bf(f1.z); r[7] = (short)f2bf(f1.w);
    *(short8*)(dst + idx) = r;
}

// ---- stage one 256x32 tile: linear LDS dest, inverse-swizzled global source.
// (verified in rounds 2/4: passed, SQ_LDS_BANK_CONFLICT = 0)
// Linear byte off = i*8192 + w*1024 + l*16 -> row = i*128 + w*16 + (l>>2), phys slot = l&3.
// Logical k-chunk at phys slot p of row r is p ^ ((r>>1)&3) -> source kof = (l&3)^((l>>3)&3).
__device__ __forceinline__ void stage_region(const short* __restrict__ gsrc, short* reg,
                                             int w, int l, int k0) {
    const int r0 = w * 16 + (l >> 2);
    const int kof = ((l & 3) ^ ((l >> 3) & 3)) * 8;
#pragma unroll
    for (int i = 0; i < 2; ++i) {
        gload16(gsrc + (size_t)(i * 128 + r0) * DDIM + k0 + kof,
                (char*)reg + i * 8192 + w * 1024 + l * 16);
    }
}

// swizzled ds_read of an 8-bf16 fragment at logical (row, 16B-slot hi) in a 256x32 buffer.
// 64B rows, phys slot = hi ^ ((row>>1)&3): conflict-free (round-2 measured 0).
__device__ __forceinline__ short8 ldsfrag32(const short* reg, int row, int hi) {
    return *(const short8*)((const char*)reg + row * 64 + ((hi ^ ((row >> 1) & 3)) << 4));
}

// constant-index select for a dynamic lane of a floatx4 (avoids dynamic GEP)
__device__ __forceinline__ float vsel4(floatx4 v, int j) {
    return (j == 0) ? v[0] : (j == 1) ? v[1] : (j == 2) ? v[2] : v[3];
}

// ---------------- fused 256^2 GEMM + per-tile partial LSE ----------------
// grid: 1280 blocks (16x16 tiles x 5 pairs), 512 threads (8 waves, 2M x 4N).
// Occupancy pivot (round-4 lesson): 4 schedules at 1 block/CU all hit 32% MfmaUtil —
// barrier-locked waves serialize the LDS-read and MFMA windows CU-wide. BK=32 with
// 64 KiB LDS fits 2 blocks/CU; the co-resident block's compute covers this block's
// stage drain (m114 TLP; 2-phase ~= 92% of 8-phase when occupancy is adequate, m230).
__launch_bounds__(512, 4)
__global__ void gemm_lse_kernel(const short* __restrict__ mats, const float* __restrict__ scale_p,
                                float* __restrict__ rowpart, float* __restrict__ colpart,
                                float* __restrict__ diag) {
    extern __shared__ char smem[];
    short* As = (short*)smem;                         // [2][8192]  (32 KiB)
    short* Bs = (short*)(smem + 32768);               // [2][8192]  (32 KiB)
    // LSE scratch OVERLAYS the staging buffers — only used after the K-loop's final
    // barrier, when all waves are done reading As/Bs.
    float* rowLse = (float*)smem;                     // [4][256]
    float* colLse = rowLse + 4 * 256;                 // [2][256]

    const int tid = threadIdx.x;
    const int w = tid >> 6, l = tid & 63;
    const int wr = w >> 2, wc = w & 3;

    // bijective XCD swizzle: nwg = 1280 = 8 * 160
    const int orig = blockIdx.x;
    const int swz = (orig & 7) * 160 + (orig >> 3);
    const int p = swz >> 8;           // pair 0..4
    const int t = swz & 255;
    const int tileRow = t & 15, tileCol = t >> 4;

    // mats order: text(0) image(1) audio(2) depth(3); no stack arrays (rule #20)
    int ai, bi;
    switch (p) {
        case 0: ai = 2; bi = 0; break;
        case 1: ai = 2; bi = 1; break;
        case 2: ai = 3; bi = 0; break;
        case 3: ai = 3; bi = 1; break;
        default: ai = 0; bi = 1; break;
    }
    const short* Aop = mats + (size_t)ai * (BDIM * DDIM) + tileRow * 256 * DDIM;
    const short* Bop = mats + (size_t)bi * (BDIM * DDIM) + tileCol * 256 * DDIM;

    floatx4 acc[8][4];
#pragma unroll
    for (int m = 0; m < 8; ++m)
#pragma unroll
        for (int n = 0; n < 4; ++n) acc[m][n] = (floatx4)(0.f);

    const int fr = l & 15, hi = l >> 4;
    const int arow = wr * 128 + fr;   // + m*16
    const int brow = wc * 64 + fr;    // + n*16

    // prologue: stage K-tile 0 into buffer 0
    stage_region(Aop, As, w, l, 0);
    stage_region(Bop, Bs, w, l, 0);
    __syncthreads();

    for (int kt = 0; kt < KT32; ++kt) {
        const short* a_buf = As + (kt & 1) * RSH;
        const short* b_buf = Bs + (kt & 1) * RSH;

        // issue next tile's async stages up front (drained by end-of-iter barrier);
        // the co-resident block computes while these are in flight.
        if (kt < KT32 - 1) {
            stage_region(Aop, As + ((kt + 1) & 1) * RSH, w, l, (kt + 1) * 32);
            stage_region(Bop, Bs + ((kt + 1) & 1) * RSH, w, l, (kt + 1) * 32);
        }

        // B fragments for the whole K-tile (16 VGPRs)
        short8 bfr[4];
#pragma unroll
        for (int n = 0; n < 4; ++n)
            bfr[n] = ldsfrag32(b_buf, brow + n * 16, hi);

#pragma unroll
        for (int m = 0; m < 8; ++m) {
            short8 afr = ldsfrag32(a_buf, arow + m * 16, hi);
            __builtin_amdgcn_s_setprio(1);
#pragma unroll
            for (int n = 0; n < 4; ++n)
                acc[m][n] = __builtin_amdgcn_mfma_f32_16x16x32_bf16(afr, bfr[n], acc[m][n], 0, 0, 0);
            __builtin_amdgcn_s_setprio(0);
        }
        __syncthreads();   // drains vmcnt: next buffer fully staged, all waves done reading
    }

    // scale
    const float s = scale_p[0];
#pragma unroll
    for (int m = 0; m < 8; ++m)
#pragma unroll
        for (int n = 0; n < 4; ++n)
#pragma unroll
            for (int j = 0; j < 4; ++j) acc[m][n][j] *= s;

    // C/D layout: out[A-row: m*16+hi*4+j][B-row: n*16+fr] = acc[m][n][j]

    // ---- row partial LSE over this wave's 64 cols ----
#pragma unroll
    for (int m = 0; m < 8; ++m) {
#pragma unroll
        for (int j = 0; j < 4; ++j) {
            float mx = -3.0e38f;
#pragma unroll
            for (int n = 0; n < 4; ++n) mx = fmaxf(mx, acc[m][n][j]);
#pragma unroll
            for (int off = 1; off < 16; off <<= 1) mx = fmaxf(mx, __shfl_xor(mx, off));
            float sm = 0.f;
#pragma unroll
            for (int n = 0; n < 4; ++n) sm += __expf(acc[m][n][j] - mx);
#pragma unroll
            for (int off = 1; off < 16; off <<= 1) sm += __shfl_xor(sm, off);
            if (fr == 0)
                rowLse[wc * 256 + wr * 128 + m * 16 + hi * 4 + j] = mx + __logf(sm);
        }
    }

    // ---- col partial LSE over this wave's 128 rows ----
#pragma unroll
    for (int n = 0; n < 4; ++n) {
        float mx = -3.0e38f;
#pragma unroll
        for (int m = 0; m < 8; ++m)
#pragma unroll
            for (int j = 0; j < 4; ++j) mx = fmaxf(mx, acc[m][n][j]);
        mx = fmaxf(mx, __shfl_xor(mx, 16));
        mx = fmaxf(mx, __shfl_xor(mx, 32));
        float sm = 0.f;
#pragma unroll
        for (int m = 0; m < 8; ++m)
#pragma unroll
            for (int j = 0; j < 4; ++j) sm += __expf(acc[m][n][j] - mx);
        sm += __shfl_xor(sm, 16);
        sm += __shfl_xor(sm, 32);
        if (hi == 0)
            colLse[wr * 256 + wc * 64 + n * 16 + fr] = mx + __logf(sm);
    }

    // ---- diagonal: all acc[] array indices compile-time constant ----
    if (tileRow == tileCol && (wc >> 1) == wr) {
        if (hi == (fr >> 2)) {
            const int j = fr & 3;   // dynamic VECTOR lane only (select chain)
            float* dst = diag + p * BDIM + tileRow * 256 + wc * 64 + fr;
            if ((wc & 1) == 0) {
                dst[0]  = vsel4(acc[0][0], j);
                dst[16] = vsel4(acc[1][1], j);
                dst[32] = vsel4(acc[2][2], j);
                dst[48] = vsel4(acc[3][3], j);
            } else {
                dst[0]  = vsel4(acc[4][0], j);
                dst[16] = vsel4(acc[5][1], j);
                dst[32] = vsel4(acc[6][2], j);
                dst[48] = vsel4(acc[7][3], j);
            }
        }
    }

    __syncthreads();

    // combine partials: threads 0-255 rows, 256-511 cols
    if (tid < 256) {
        float v0 = rowLse[tid], v1 = rowLse[256 + tid], v2 = rowLse[512 + tid], v3 = rowLse[768 + tid];
        float mm = fmaxf(fmaxf(v0, v1), fmaxf(v2, v3));
        float r = mm + __logf(__expf(v0 - mm) + __expf(v1 - mm) + __expf(v2 - mm) + __expf(v3 - mm));
        rowpart[((size_t)p * BDIM + tileRow * 256 + tid) * TW + tileCol] = r;
    } else {
        int c = tid - 256;
        float v0 = colLse[c], v1 = colLse[256 + c];
        float mm = fmaxf(v0, v1);
        float r = mm + __logf(__expf(v0 - mm) + __expf(v1 - mm));
        colpart[((size_t)p * BDIM + tileCol * 256 + c) * TW + tileRow] = r;
    }
}

// ---------------- per-row final LSE + loss partial sums ----------------
__global__ void reduce_kernel(const float* __restrict__ rowpart, const float* __restrict__ colpart,
                              const float* __restrict__ diag, float* __restrict__ partials) {
    int p = blockIdx.y;
    int i = blockIdx.x * 256 + threadIdx.x;
    size_t gi = (size_t)p * BDIM + i;

    const float* rp = rowpart + gi * TW;
    float mx = -3.0e38f;
#pragma unroll
    for (int t = 0; t < TW; ++t) mx = fmaxf(mx, rp[t]);
    float sm = 0.f;
#pragma unroll
    for (int t = 0; t < TW; ++t) sm += __expf(rp[t] - mx);
    float rl = mx + __logf(sm);

    const float* cp = colpart + gi * TW;
    mx = -3.0e38f;
#pragma unroll
    for (int t = 0; t < TW; ++t) mx = fmaxf(mx, cp[t]);
    sm = 0.f;
#pragma unroll
    for (int t = 0; t < TW; ++t) sm += __expf(cp[t] - mx);
    float cl = mx + __logf(sm);

    float contrib = rl + cl - 2.f * diag[gi];

    __shared__ float red[256];
    red[threadIdx.x] = contrib;
    __syncthreads();
    for (int s2 = 128; s2 > 0; s2 >>= 1) {
        if (threadIdx.x < (unsigned)s2) red[threadIdx.x] += red[threadIdx.x + s2];
        __syncthreads();
    }
    if (threadIdx.x == 0) partials[p * 16 + blockIdx.x] = red[0];
}

__global__ void final_kernel(const float* __restrict__ partials, float* __restrict__ out) {
    __shared__ float red[128];
    int t = threadIdx.x;
    red[t] = (t < NPAIRS * 16) ? partials[t] : 0.f;
    __syncthreads();
    for (int s2 = 64; s2 > 0; s2 >>= 1) {
        if (t < s2) red[t] += red[t + s2];
        __syncthreads();
    }
    if (t == 0) out[0] = red[0] * (1.f / (2.f * BDIM));
}

extern "C" void kernel_launch(void* const* d_in, const int* in_sizes, int n_in,
                              void* d_out, int out_size, void* d_ws, size_t ws_size,
                              hipStream_t stream) {
    const float* text  = (const float*)d_in[0];
    const float* image = (const float*)d_in[1];
    const float* audio = (const float*)d_in[2];
    const float* depth = (const float*)d_in[3];
    const float* scale = (const float*)d_in[4];
    float* out = (float*)d_out;

    char* ws = (char*)d_ws;
    short* mats = (short*)ws;                                   // 4 * 8 MB bf16
    size_t off = (size_t)4 * BDIM * DDIM * 2;
    float* rowpart = (float*)(ws + off); off += (size_t)NPAIRS * BDIM * TW * 4;
    float* colpart = (float*)(ws + off); off += (size_t)NPAIRS * BDIM * TW * 4;
    float* diag    = (float*)(ws + off); off += (size_t)NPAIRS * BDIM * 4;
    float* partials= (float*)(ws + off); off += NPAIRS * 16 * 4;

    const int smem_bytes = 65536;   // 64 KiB staging (LSE scratch overlays it)
    hipFuncSetAttribute((const void*)gemm_lse_kernel,
                        hipFuncAttributeMaxDynamicSharedMemorySize, smem_bytes);

    cast_kernel<<<dim3(2048, 4), 256, 0, stream>>>(text, image, audio, depth, mats);
    gemm_lse_kernel<<<dim3(1280), 512, smem_bytes, stream>>>(mats, scale, rowpart, colpart, diag);
    reduce_kernel<<<dim3(16, NPAIRS), 256, 0, stream>>>(rowpart, colpart, diag, partials);
    final_kernel<<<1, 128, 0, stream>>>(partials, out);
}

// Round 6
// 414.473 us; speedup vs baseline: 2.3014x; 2.3014x over previous
//
#include <hip/hip_runtime.h>
#include <hip/hip_bf16.h>

#define BDIM 4096
#define DDIM 1024
#define NPAIRS 5
#define TW 16            // 4096/256 tiles per side

typedef __attribute__((ext_vector_type(8))) short short8;
typedef __attribute__((ext_vector_type(4))) float floatx4;

__device__ __forceinline__ void gload16(const void* g, void* l) {
    __builtin_amdgcn_global_load_lds((const __attribute__((address_space(1))) void*)g,
                                     (__attribute__((address_space(3))) void*)l, 16, 0, 0);
}

__device__ __forceinline__ unsigned short f2bf(float f) {
    unsigned u = __float_as_uint(f);
    u = (u + 0x7FFFu + ((u >> 16) & 1u)) >> 16;   // RNE f32->bf16
    return (unsigned short)u;
}

// ---------------- cast f32 -> bf16, 4 matrices ----------------
__global__ void cast_kernel(const float* __restrict__ t, const float* __restrict__ im,
                            const float* __restrict__ au, const float* __restrict__ de,
                            short* __restrict__ out) {
    const float* src;
    switch (blockIdx.y) {
        case 0: src = t; break;
        case 1: src = im; break;
        case 2: src = au; break;
        default: src = de; break;
    }
    short* dst = out + (size_t)blockIdx.y * (BDIM * DDIM);
    int idx = (blockIdx.x * 256 + threadIdx.x) * 8;
    float4 f0 = *(const float4*)(src + idx);
    float4 f1 = *(const float4*)(src + idx + 4);
    short8 r;
    r[0] = (short)f2bf(f0.x); r[1] = (short)f2bf(f0.y);
    r[2] = (short)f2bf(f0.z); r[3] = (short)f2bf(f0.w);
    r[4] = (short)f2bf(f1.x); r[5] = (short)f2bf(f1.y);
    r[6] = (short)f2bf(f1.z); r[7] = (short)f2bf(f1.w);
    *(short8*)(dst + idx) = r;
}

// ---- stage HALF of one 256x64 tile (ih=0,1): linear LDS dest, inverse-swizzled
// global source (round-0-verified layout: 0 bank conflicts, refcheck'd).
// dst byte = s*1024 + lane*16 -> row = s*8 + (l>>3), phys 16B-slot = l&7;
// logical k-chunk at phys slot p of row r is p ^ (r&7) -> src kof = ((l&7)^(l>>3))*8.
__device__ __forceinline__ void stage_half(const short* __restrict__ gsrc, void* lbase,
                                           int w, int l, int k0, int ih) {
    const int lr = l >> 3;
    const int lc = ((l & 7) ^ lr) * 8;
#pragma unroll
    for (int j = 0; j < 2; ++j) {
        int s = w * 4 + ih * 2 + j;
        gload16(gsrc + (size_t)(s * 8 + lr) * DDIM + k0 + lc, (char*)lbase + s * 1024);
    }
}

// swizzled ds_read of an 8-bf16 fragment at logical (row, kofShorts) in a 256x64 tile
__device__ __forceinline__ short8 ldsfrag(const short* buf, int row, int kofShorts) {
    int slot = kofShorts >> 3;
    return *(const short8*)((const char*)buf + row * 128 + ((slot ^ (row & 7)) << 4));
}

// constant-index select for a dynamic lane of a floatx4 (avoids dynamic GEP)
__device__ __forceinline__ float vsel4(floatx4 v, int j) {
    return (j == 0) ? v[0] : (j == 1) ? v[1] : (j == 2) ? v[2] : v[3];
}

// ---- read blocks (8 or 4 ds_read_b128 each; targets ping-pong per Gray schedule) ----
#define RD_A(DST, BUF, MH) \
    _Pragma("unroll") for (int kk_ = 0; kk_ < 2; ++kk_) \
    _Pragma("unroll") for (int m_ = 0; m_ < 4; ++m_) \
        DST[kk_ * 4 + m_] = ldsfrag(BUF, arow + ((MH) * 4 + m_) * 16, kk_ * 32 + hi * 8);

#define RD_B(DST, BUF, NH) \
    _Pragma("unroll") for (int kk_ = 0; kk_ < 2; ++kk_) \
    _Pragma("unroll") for (int n_ = 0; n_ < 2; ++n_) \
        DST[kk_ * 2 + n_] = ldsfrag(BUF, brow + ((NH) * 2 + n_) * 16, kk_ * 32 + hi * 8);

// 16-MFMA quadrant cluster; all acc indices compile-time constant (rule #20)
#define MF(ASET, BSET, MH, NB) \
    _Pragma("unroll") for (int kk_ = 0; kk_ < 2; ++kk_) \
    _Pragma("unroll") for (int m_ = 0; m_ < 4; ++m_) \
    _Pragma("unroll") for (int n_ = 0; n_ < 2; ++n_) \
        acc[(MH) * 4 + m_][(NB) + n_] = __builtin_amdgcn_mfma_f32_16x16x32_bf16( \
            ASET[kk_ * 4 + m_], BSET[kk_ * 2 + n_], acc[(MH) * 4 + m_][(NB) + n_], 0, 0, 0);

#define WV(n) asm volatile("s_waitcnt vmcnt(" #n ")" ::: "memory");

// Phase: [reads(next ops)][bar][lgkm(n_this)][MFMA][stage][vmcnt?][bar]
// - counted lgkm: only the PREVIOUS phase's reads must retire -> this phase's reads
//   drain on the LDS pipe during the MFMA window (the overlap lever, T3+T4).
// - stage after MFMA + WAITV-before-bar/first-read-after-bar: race rule (r3 lesson).
#define PHASE(RDBLK, NL, MFBLK, STBLK, WVBLK) \
    RDBLK \
    __builtin_amdgcn_sched_barrier(0); \
    __builtin_amdgcn_s_barrier(); \
    asm volatile("s_waitcnt lgkmcnt(" #NL ")" ::: "memory"); \
    __builtin_amdgcn_sched_barrier(0); \
    __builtin_amdgcn_s_setprio(1); \
    MFBLK \
    __builtin_amdgcn_s_setprio(0); \
    STBLK \
    WVBLK \
    __builtin_amdgcn_sched_barrier(0); \
    __builtin_amdgcn_s_barrier();

// ---------------- fused 256^2 GEMM + per-tile partial LSE ----------------
// grid: 1280 blocks (16x16 tiles x 5 pairs), 512 threads (8 waves, 2M x 4N).
// m201 Gray-code 8-phase cycle over tile pairs (even tile -> buf0, odd -> buf1):
//   MFMA: aL·b0, aH·b0, aH·b1, aL·b1 | aH·b0', aL·b0', aL·b1', aH·b1'
//   reads (1 phase ahead): aH,bb1,bb0',aH' | aL',bb1',bb0'',aL''  = 8,4,4,8 per phase
//   stages: A(T+1)@0,1  B(T+2)@2,3  A(T+2)@4,5  B(T+3)@6,7 (after MFMA cluster)
//   waits: lgkm = reads issued this phase; vmcnt(4)@1,5 / vmcnt(2)@2,6
// Register budget: aL[8]+aH[8]+bb0[4]+bb1[4] = 96 VGPR + acc 128 AGPR -> fits 256.
__launch_bounds__(512, 1)
__global__ void gemm_lse_kernel(const short* __restrict__ mats, const float* __restrict__ scale_p,
                                float* __restrict__ rowpart, float* __restrict__ colpart,
                                float* __restrict__ diag) {
    extern __shared__ char smem[];
    short* Abuf0 = (short*)smem;                      // [256][64] tile, even tiles
    short* Abuf1 = Abuf0 + 16384;                     // odd tiles
    short* Bbuf0 = (short*)(smem + 65536);
    short* Bbuf1 = Bbuf0 + 16384;
    float* rowLse = (float*)(smem + 131072);          // [4][256]
    float* colLse = rowLse + 4 * 256;                 // [2][256]

    const int tid = threadIdx.x;
    const int w = tid >> 6, l = tid & 63;
    const int wr = w >> 2, wc = w & 3;

    // bijective XCD swizzle: nwg = 1280 = 8 * 160
    const int orig = blockIdx.x;
    const int swz = (orig & 7) * 160 + (orig >> 3);
    const int p = swz >> 8;           // pair 0..4
    const int t = swz & 255;
    const int tileRow = t & 15, tileCol = t >> 4;

    // mats order: text(0) image(1) audio(2) depth(3); no stack arrays (rule #20)
    int ai, bi;
    switch (p) {
        case 0: ai = 2; bi = 0; break;
        case 1: ai = 2; bi = 1; break;
        case 2: ai = 3; bi = 0; break;
        case 3: ai = 3; bi = 1; break;
        default: ai = 0; bi = 1; break;
    }
    const short* Aop = mats + (size_t)ai * (BDIM * DDIM) + tileRow * 256 * DDIM;
    const short* Bop = mats + (size_t)bi * (BDIM * DDIM) + tileCol * 256 * DDIM;

    floatx4 acc[8][4];
#pragma unroll
    for (int m = 0; m < 8; ++m)
#pragma unroll
        for (int n = 0; n < 4; ++n) acc[m][n] = (floatx4)(0.f);

    const int fr = l & 15, hi = l >> 4;
    const int arow = wr * 128 + fr;   // + M*16
    const int brow = wc * 64 + fr;    // + N*16

    short8 aL[8], aH[8], bb0[4], bb1[4];

    // prologue: stage A(0),B(0),B(1); retire A(0),B(0) (vmcnt 4, leaves B(1)); barrier;
    // pre-read Ph0 operands (12 reads, retired by Ph0's lgkm(8)).
    stage_half(Aop, Abuf0, w, l, 0, 0);  stage_half(Aop, Abuf0, w, l, 0, 1);
    stage_half(Bop, Bbuf0, w, l, 0, 0);  stage_half(Bop, Bbuf0, w, l, 0, 1);
    stage_half(Bop, Bbuf1, w, l, 64, 0); stage_half(Bop, Bbuf1, w, l, 64, 1);
    WV(4)
    __builtin_amdgcn_sched_barrier(0);
    __builtin_amdgcn_s_barrier();
    RD_A(aL, Abuf0, 0)
    RD_B(bb0, Bbuf0, 0)

#pragma unroll 1
    for (int tp = 0; tp < 7; ++tp) {
        const int kA1 = (2 * tp + 1) * 64;   // A(T+1)
        const int kE2 = (2 * tp + 2) * 64;   // B(T+2), A(T+2)
        const int kO3 = (2 * tp + 3) * 64;   // B(T+3)
        PHASE(RD_A(aH, Abuf0, 1), 8, MF(aL, bb0, 0, 0), stage_half(Aop, Abuf1, w, l, kA1, 0);, )
        PHASE(RD_B(bb1, Bbuf0, 1), 4, MF(aH, bb0, 1, 0), stage_half(Aop, Abuf1, w, l, kA1, 1);, WV(4))
        PHASE(RD_B(bb0, Bbuf1, 0), 4, MF(aH, bb1, 1, 2), stage_half(Bop, Bbuf0, w, l, kE2, 0);, WV(2))
        PHASE(RD_A(aH, Abuf1, 1), 8, MF(aL, bb1, 0, 2), stage_half(Bop, Bbuf0, w, l, kE2, 1);, )
        PHASE(RD_A(aL, Abuf1, 0), 8, MF(aH, bb0, 1, 0), stage_half(Aop, Abuf0, w, l, kE2, 0);, )
        PHASE(RD_B(bb1, Bbuf1, 1), 4, MF(aL, bb0, 0, 0), stage_half(Aop, Abuf0, w, l, kE2, 1);, WV(4))
        PHASE(RD_B(bb0, Bbuf0, 0), 4, MF(aL, bb1, 0, 2), stage_half(Bop, Bbuf1, w, l, kO3, 0);, WV(2))
        PHASE(RD_A(aL, Abuf0, 0), 8, MF(aH, bb1, 1, 2), stage_half(Bop, Bbuf1, w, l, kO3, 1);, )
    }
    // tail pair: tiles 14,15 — stage only A(15); drain vmcnt at Ph2; no reads at Ph6/7
    {
        const int kA1 = 15 * 64;
        PHASE(RD_A(aH, Abuf0, 1), 8, MF(aL, bb0, 0, 0), stage_half(Aop, Abuf1, w, l, kA1, 0);, )
        PHASE(RD_B(bb1, Bbuf0, 1), 4, MF(aH, bb0, 1, 0), stage_half(Aop, Abuf1, w, l, kA1, 1);, WV(4))
        PHASE(RD_B(bb0, Bbuf1, 0), 4, MF(aH, bb1, 1, 2), , WV(0))
        PHASE(RD_A(aH, Abuf1, 1), 8, MF(aL, bb1, 0, 2), , )
        PHASE(RD_A(aL, Abuf1, 0), 8, MF(aH, bb0, 1, 0), , )
        PHASE(RD_B(bb1, Bbuf1, 1), 4, MF(aL, bb0, 0, 0), , )
        PHASE(, 0, MF(aL, bb1, 0, 2), , )
        PHASE(, 0, MF(aH, bb1, 1, 2), , )
    }

    // scale
    const float s = scale_p[0];
#pragma unroll
    for (int m = 0; m < 8; ++m)
#pragma unroll
        for (int n = 0; n < 4; ++n)
#pragma unroll
            for (int j = 0; j < 4; ++j) acc[m][n][j] *= s;

    // C/D layout: out[A-row: m*16+hi*4+j][B-row: n*16+fr] = acc[m][n][j]

    // ---- row partial LSE over this wave's 64 cols ----
#pragma unroll
    for (int m = 0; m < 8; ++m) {
#pragma unroll
        for (int j = 0; j < 4; ++j) {
            float mx = -3.0e38f;
#pragma unroll
            for (int n = 0; n < 4; ++n) mx = fmaxf(mx, acc[m][n][j]);
#pragma unroll
            for (int off = 1; off < 16; off <<= 1) mx = fmaxf(mx, __shfl_xor(mx, off));
            float sm = 0.f;
#pragma unroll
            for (int n = 0; n < 4; ++n) sm += __expf(acc[m][n][j] - mx);
#pragma unroll
            for (int off = 1; off < 16; off <<= 1) sm += __shfl_xor(sm, off);
            if (fr == 0)
                rowLse[wc * 256 + wr * 128 + m * 16 + hi * 4 + j] = mx + __logf(sm);
        }
    }

    // ---- col partial LSE over this wave's 128 rows ----
#pragma unroll
    for (int n = 0; n < 4; ++n) {
        float mx = -3.0e38f;
#pragma unroll
        for (int m = 0; m < 8; ++m)
#pragma unroll
            for (int j = 0; j < 4; ++j) mx = fmaxf(mx, acc[m][n][j]);
        mx = fmaxf(mx, __shfl_xor(mx, 16));
        mx = fmaxf(mx, __shfl_xor(mx, 32));
        float sm = 0.f;
#pragma unroll
        for (int m = 0; m < 8; ++m)
#pragma unroll
            for (int j = 0; j < 4; ++j) sm += __expf(acc[m][n][j] - mx);
        sm += __shfl_xor(sm, 16);
        sm += __shfl_xor(sm, 32);
        if (hi == 0)
            colLse[wr * 256 + wc * 64 + n * 16 + fr] = mx + __logf(sm);
    }

    // ---- diagonal: all acc[] array indices compile-time constant ----
    if (tileRow == tileCol && (wc >> 1) == wr) {
        if (hi == (fr >> 2)) {
            const int j = fr & 3;   // dynamic VECTOR lane only (select chain)
            float* dst = diag + p * BDIM + tileRow * 256 + wc * 64 + fr;
            if ((wc & 1) == 0) {
                dst[0]  = vsel4(acc[0][0], j);
                dst[16] = vsel4(acc[1][1], j);
                dst[32] = vsel4(acc[2][2], j);
                dst[48] = vsel4(acc[3][3], j);
            } else {
                dst[0]  = vsel4(acc[4][0], j);
                dst[16] = vsel4(acc[5][1], j);
                dst[32] = vsel4(acc[6][2], j);
                dst[48] = vsel4(acc[7][3], j);
            }
        }
    }

    __syncthreads();

    // combine partials: threads 0-255 rows, 256-511 cols
    if (tid < 256) {
        float v0 = rowLse[tid], v1 = rowLse[256 + tid], v2 = rowLse[512 + tid], v3 = rowLse[768 + tid];
        float mm = fmaxf(fmaxf(v0, v1), fmaxf(v2, v3));
        float r = mm + __logf(__expf(v0 - mm) + __expf(v1 - mm) + __expf(v2 - mm) + __expf(v3 - mm));
        rowpart[((size_t)p * BDIM + tileRow * 256 + tid) * TW + tileCol] = r;
    } else {
        int c = tid - 256;
        float v0 = colLse[c], v1 = colLse[256 + c];
        float mm = fmaxf(v0, v1);
        float r = mm + __logf(__expf(v0 - mm) + __expf(v1 - mm));
        colpart[((size_t)p * BDIM + tileCol * 256 + c) * TW + tileRow] = r;
    }
}

// ---------------- per-row final LSE + loss partial sums ----------------
__global__ void reduce_kernel(const float* __restrict__ rowpart, const float* __restrict__ colpart,
                              const float* __restrict__ diag, float* __restrict__ partials) {
    int p = blockIdx.y;
    int i = blockIdx.x * 256 + threadIdx.x;
    size_t gi = (size_t)p * BDIM + i;

    const float* rp = rowpart + gi * TW;
    float mx = -3.0e38f;
#pragma unroll
    for (int t = 0; t < TW; ++t) mx = fmaxf(mx, rp[t]);
    float sm = 0.f;
#pragma unroll
    for (int t = 0; t < TW; ++t) sm += __expf(rp[t] - mx);
    float rl = mx + __logf(sm);

    const float* cp = colpart + gi * TW;
    mx = -3.0e38f;
#pragma unroll
    for (int t = 0; t < TW; ++t) mx = fmaxf(mx, cp[t]);
    sm = 0.f;
#pragma unroll
    for (int t = 0; t < TW; ++t) sm += __expf(cp[t] - mx);
    float cl = mx + __logf(sm);

    float contrib = rl + cl - 2.f * diag[gi];

    __shared__ float red[256];
    red[threadIdx.x] = contrib;
    __syncthreads();
    for (int s2 = 128; s2 > 0; s2 >>= 1) {
        if (threadIdx.x < (unsigned)s2) red[threadIdx.x] += red[threadIdx.x + s2];
        __syncthreads();
    }
    if (threadIdx.x == 0) partials[p * 16 + blockIdx.x] = red[0];
}

__global__ void final_kernel(const float* __restrict__ partials, float* __restrict__ out) {
    __shared__ float red[128];
    int t = threadIdx.x;
    red[t] = (t < NPAIRS * 16) ? partials[t] : 0.f;
    __syncthreads();
    for (int s2 = 64; s2 > 0; s2 >>= 1) {
        if (t < s2) red[t] += red[t + s2];
        __syncthreads();
    }
    if (t == 0) out[0] = red[0] * (1.f / (2.f * BDIM));
}

extern "C" void kernel_launch(void* const* d_in, const int* in_sizes, int n_in,
                              void* d_out, int out_size, void* d_ws, size_t ws_size,
                              hipStream_t stream) {
    const float* text  = (const float*)d_in[0];
    const float* image = (const float*)d_in[1];
    const float* audio = (const float*)d_in[2];
    const float* depth = (const float*)d_in[3];
    const float* scale = (const float*)d_in[4];
    float* out = (float*)d_out;

    char* ws = (char*)d_ws;
    short* mats = (short*)ws;                                   // 4 * 8 MB bf16
    size_t off = (size_t)4 * BDIM * DDIM * 2;
    float* rowpart = (float*)(ws + off); off += (size_t)NPAIRS * BDIM * TW * 4;
    float* colpart = (float*)(ws + off); off += (size_t)NPAIRS * BDIM * TW * 4;
    float* diag    = (float*)(ws + off); off += (size_t)NPAIRS * BDIM * 4;
    float* partials= (float*)(ws + off); off += NPAIRS * 16 * 4;

    const int smem_bytes = 131072 + 4 * 256 * 4 + 2 * 256 * 4;  // 137216
    hipFuncSetAttribute((const void*)gemm_lse_kernel,
                        hipFuncAttributeMaxDynamicSharedMemorySize, smem_bytes);

    cast_kernel<<<dim3(2048, 4), 256, 0, stream>>>(text, image, audio, depth, mats);
    gemm_lse_kernel<<<dim3(1280), 512, smem_bytes, stream>>>(mats, scale, rowpart, colpart, diag);
    reduce_kernel<<<dim3(16, NPAIRS), 256, 0, stream>>>(rowpart, colpart, diag, partials);
    final_kernel<<<1, 128, 0, stream>>>(partials, out);
}